// Round 1
// baseline (1095.049 us; speedup 1.0000x reference)
//
#include <hip/hip_runtime.h>

typedef __bf16 bf16;
typedef bf16 bf16x8 __attribute__((ext_vector_type(8)));
typedef bf16 bf16x4 __attribute__((ext_vector_type(4)));
typedef float f32x4 __attribute__((ext_vector_type(4)));

#define S_LEN 1024
#define DM    1024
#define NH    16
#define HD    64
#define NB    8
#define KDIM  1024
#define NEGV  (-1e9f)

// epilogue modes
#define EPI_HEADS 0  // write bf16 [N,H,S,D]  (Q,K projections)
#define EPI_VT    1  // write bf16 [N,H,D,S]  (V projection, transposed)
#define EPI_CTX   2  // batched PV: write bf16 ctx [N,S,DM]
#define EPI_OUT   3  // write fp32 [M,N] + bias (final projection)

// ---------------------------------------------------------------------------
// Cast the 4 weight matrices (each 1024x1024 fp32) to bf16 in workspace.
// ---------------------------------------------------------------------------
__global__ __launch_bounds__(256) void cast_weights(
    const float* __restrict__ a, const float* __restrict__ b,
    const float* __restrict__ c, const float* __restrict__ d,
    bf16* __restrict__ out)
{
    int i = blockIdx.x * 256 + threadIdx.x;   // each thread: 4 floats
    size_t idx = (size_t)i * 4;
    int which = (int)(idx >> 20);             // 1048576 elems per weight
    int off   = (int)(idx & 1048575);
    const float* srcs[4] = {a, b, c, d};
    float4 v = *(const float4*)&srcs[which][off];
    bf16x4 o = { (bf16)v.x, (bf16)v.y, (bf16)v.z, (bf16)v.w };
    *(bf16x4*)&out[(size_t)which * 1048576 + off] = o;
}

// ---------------------------------------------------------------------------
// NT GEMM: C[M,N] = A[M,K] @ B[N,K]^T (+bias), K = 1024.
// A fp32 (converted at staging) or bf16; B bf16. 16x16x32 bf16 MFMA.
// Block 256 threads = 4 waves in 2x2; tile BM x BN, BK = 32, single-buffered.
// ---------------------------------------------------------------------------
template<int BM, int BN, int AF32, int EPI>
__global__ __launch_bounds__(256) void gemm_nt(
    const void* __restrict__ Ap, const bf16* __restrict__ Bp,
    const float* __restrict__ bias, void* __restrict__ Cp,
    long batchStrideA, long batchStrideB)
{
    constexpr int WM = BM / 2, WN = BN / 2, TM = WM / 16, TN = WN / 16;
    __shared__ bf16 As[BM][32];
    __shared__ bf16 Bs[BN][32];

    const int tid    = threadIdx.x;
    const int l      = tid & 63;
    const int wv     = tid >> 6;
    const int wr     = wv >> 1, wc = wv & 1;
    const int lane15 = l & 15, quad = l >> 4;
    const int row0   = blockIdx.x * BM;
    const int col0   = blockIdx.y * BN;
    const int bz     = blockIdx.z;

    const float* Af = (const float*)Ap + (size_t)bz * batchStrideA;
    const bf16*  Ab = (const bf16*) Ap + (size_t)bz * batchStrideA;
    const bf16*  Bb = Bp + (size_t)bz * batchStrideB;

    f32x4 acc[TM][TN];
    #pragma unroll
    for (int i = 0; i < TM; ++i)
        #pragma unroll
        for (int j = 0; j < TN; ++j)
            acc[i][j] = (f32x4){0.f, 0.f, 0.f, 0.f};

    for (int k0 = 0; k0 < KDIM; k0 += 32) {
        // ---- stage A tile (BM x 32) ----
        if (AF32) {
            #pragma unroll
            for (int it = 0; it < (BM * 32) / (256 * 4); ++it) {
                int chunk = it * 256 + tid;
                int r = chunk >> 3, cc = (chunk & 7) << 2;
                float4 v = *(const float4*)&Af[(size_t)(row0 + r) * KDIM + k0 + cc];
                bf16x4 o = { (bf16)v.x, (bf16)v.y, (bf16)v.z, (bf16)v.w };
                *(bf16x4*)&As[r][cc] = o;
            }
        } else {
            #pragma unroll
            for (int it = 0; it < (BM * 32) / (256 * 8); ++it) {
                int chunk = it * 256 + tid;
                int r = chunk >> 2, cc = (chunk & 3) << 3;
                *(bf16x8*)&As[r][cc] =
                    *(const bf16x8*)&Ab[(size_t)(row0 + r) * KDIM + k0 + cc];
            }
        }
        // ---- stage B tile (BN x 32) ----
        #pragma unroll
        for (int it = 0; it < (BN * 32) / (256 * 8); ++it) {
            int chunk = it * 256 + tid;
            int r = chunk >> 2, cc = (chunk & 3) << 3;
            *(bf16x8*)&Bs[r][cc] =
                *(const bf16x8*)&Bb[(size_t)(col0 + r) * KDIM + k0 + cc];
        }
        __syncthreads();

        bf16x8 afr[TM], bfr[TN];
        #pragma unroll
        for (int tm = 0; tm < TM; ++tm)
            afr[tm] = *(const bf16x8*)&As[wr * WM + tm * 16 + lane15][quad * 8];
        #pragma unroll
        for (int tn = 0; tn < TN; ++tn)
            bfr[tn] = *(const bf16x8*)&Bs[wc * WN + tn * 16 + lane15][quad * 8];
        #pragma unroll
        for (int tm = 0; tm < TM; ++tm)
            #pragma unroll
            for (int tn = 0; tn < TN; ++tn)
                acc[tm][tn] = __builtin_amdgcn_mfma_f32_16x16x32_bf16(
                    afr[tm], bfr[tn], acc[tm][tn], 0, 0, 0);
        __syncthreads();
    }

    // ---- epilogue ----
    #pragma unroll
    for (int tm = 0; tm < TM; ++tm) {
        #pragma unroll
        for (int tn = 0; tn < TN; ++tn) {
            #pragma unroll
            for (int i = 0; i < 4; ++i) {
                int gr = row0 + wr * WM + tm * 16 + quad * 4 + i;
                int gc = col0 + wc * WN + tn * 16 + lane15;
                float vout = acc[tm][tn][i];
                if constexpr (EPI != EPI_CTX) vout += bias[gc];
                if constexpr (EPI == EPI_HEADS) {
                    int n = gr >> 10, s = gr & 1023, h = gc >> 6, d = gc & 63;
                    ((bf16*)Cp)[(((size_t)(n * NH + h) * S_LEN + s) << 6) + d] = (bf16)vout;
                } else if constexpr (EPI == EPI_VT) {
                    int n = gr >> 10, s = gr & 1023, h = gc >> 6, d = gc & 63;
                    ((bf16*)Cp)[(((size_t)(n * NH + h) * HD + d) << 10) + s] = (bf16)vout;
                } else if constexpr (EPI == EPI_CTX) {
                    int n = bz >> 4, h = bz & 15;
                    ((bf16*)Cp)[((size_t)(n * S_LEN + gr) << 10) + h * HD + gc] = (bf16)vout;
                } else { // EPI_OUT
                    ((float*)Cp)[(size_t)gr * DM + gc] = vout;
                }
            }
        }
    }
}

// ---------------------------------------------------------------------------
// Attention scores + softmax: per block = one (n, h, 16-q-row) tile.
// 4 waves; wave w owns key columns [w*256, w*256+256) = 16 tiles of 16x16.
// Writes normalized attention weights (fp32) to the w output region.
// ---------------------------------------------------------------------------
__global__ __launch_bounds__(256) void attn_softmax(
    const bf16* __restrict__ Qp, const bf16* __restrict__ Kp,
    const int* __restrict__ pad, float* __restrict__ Wout)
{
    const int qblk = blockIdx.x;
    const int h = blockIdx.y, n = blockIdx.z;
    const int bh = n * NH + h;
    const bf16* Qb = Qp + (size_t)bh * S_LEN * HD;
    const bf16* Kb = Kp + (size_t)bh * S_LEN * HD;
    float* Wb = Wout + (size_t)bh * S_LEN * S_LEN;

    const int tid = threadIdx.x;
    const int l = tid & 63, wid = tid >> 6;
    const int lane15 = l & 15, quad = l >> 4;
    const int q0 = qblk * 16;

    __shared__ int   padLds[S_LEN];
    __shared__ float redM[4][16];
    __shared__ float redS[4][16];
    for (int i = tid; i < S_LEN; i += 256) padLds[i] = pad[n * S_LEN + i];

    bf16x8 a0 = *(const bf16x8*)&Qb[(size_t)(q0 + lane15) * HD + quad * 8];
    bf16x8 a1 = *(const bf16x8*)&Qb[(size_t)(q0 + lane15) * HD + 32 + quad * 8];
    __syncthreads();

    f32x4 sc[16];
    const int colbase = wid * 256;
    #pragma unroll
    for (int t = 0; t < 16; ++t) {
        int c0 = colbase + t * 16;
        bf16x8 b0 = *(const bf16x8*)&Kb[(size_t)(c0 + lane15) * HD + quad * 8];
        bf16x8 b1 = *(const bf16x8*)&Kb[(size_t)(c0 + lane15) * HD + 32 + quad * 8];
        f32x4 a = (f32x4){0.f, 0.f, 0.f, 0.f};
        a = __builtin_amdgcn_mfma_f32_16x16x32_bf16(a0, b0, a, 0, 0, 0);
        a = __builtin_amdgcn_mfma_f32_16x16x32_bf16(a1, b1, a, 0, 0, 0);
        sc[t] = a;
    }

    // scale + causal/padding mask (exactly -1e9, like the reference)
    #pragma unroll
    for (int t = 0; t < 16; ++t) {
        int col = colbase + t * 16 + lane15;
        int pd = padLds[col];
        #pragma unroll
        for (int i = 0; i < 4; ++i) {
            int row = q0 + quad * 4 + i;
            float v = sc[t][i] * 0.03125f;   // 1/sqrt(1024)
            sc[t][i] = (col > row || pd != 0) ? NEGV : v;
        }
    }

    // row max: per-lane over tiles, shuffle over 16 lanes, LDS across waves
    float m[4];
    #pragma unroll
    for (int i = 0; i < 4; ++i) {
        float mm = sc[0][i];
        #pragma unroll
        for (int t = 1; t < 16; ++t) mm = fmaxf(mm, sc[t][i]);
        #pragma unroll
        for (int dlt = 1; dlt < 16; dlt <<= 1) mm = fmaxf(mm, __shfl_xor(mm, dlt));
        m[i] = mm;
    }
    if (lane15 == 0) {
        #pragma unroll
        for (int i = 0; i < 4; ++i) redM[wid][quad * 4 + i] = m[i];
    }
    __syncthreads();
    #pragma unroll
    for (int i = 0; i < 4; ++i) {
        int row = quad * 4 + i;
        float mm = fmaxf(fmaxf(redM[0][row], redM[1][row]),
                         fmaxf(redM[2][row], redM[3][row]));
        m[i] = mm;
    }

    // exp + row sum
    float sm[4] = {0.f, 0.f, 0.f, 0.f};
    #pragma unroll
    for (int t = 0; t < 16; ++t)
        #pragma unroll
        for (int i = 0; i < 4; ++i) {
            float p = __expf(sc[t][i] - m[i]);
            sc[t][i] = p;
            sm[i] += p;
        }
    #pragma unroll
    for (int i = 0; i < 4; ++i) {
        #pragma unroll
        for (int dlt = 1; dlt < 16; dlt <<= 1) sm[i] += __shfl_xor(sm[i], dlt);
    }
    if (lane15 == 0) {
        #pragma unroll
        for (int i = 0; i < 4; ++i) redS[wid][quad * 4 + i] = sm[i];
    }
    __syncthreads();
    float inv[4];
    #pragma unroll
    for (int i = 0; i < 4; ++i) {
        int row = quad * 4 + i;
        float s = redS[0][row] + redS[1][row] + redS[2][row] + redS[3][row];
        inv[i] = 1.f / s;
    }

    // write normalized weights
    #pragma unroll
    for (int t = 0; t < 16; ++t)
        #pragma unroll
        for (int i = 0; i < 4; ++i) {
            Wb[(size_t)(q0 + quad * 4 + i) * S_LEN + colbase + t * 16 + lane15] =
                sc[t][i] * inv[i];
        }
}

// ---------------------------------------------------------------------------
extern "C" void kernel_launch(void* const* d_in, const int* in_sizes, int n_in,
                              void* d_out, int out_size, void* d_ws, size_t ws_size,
                              hipStream_t stream)
{
    const float* q   = (const float*)d_in[0];
    const float* k   = (const float*)d_in[1];
    const float* v   = (const float*)d_in[2];
    // d_in[3] = causal_mask (triu, k=1) -- computed arithmetically instead
    const int*   pad = (const int*)  d_in[4];
    const float* Wq  = (const float*)d_in[5];
    const float* bq  = (const float*)d_in[6];
    const float* Wk  = (const float*)d_in[7];
    const float* bk  = (const float*)d_in[8];
    const float* Wv  = (const float*)d_in[9];
    const float* bv  = (const float*)d_in[10];
    const float* Wo  = (const float*)d_in[11];
    const float* bo  = (const float*)d_in[12];

    float* x_out = (float*)d_out;                       // [8,1024,1024]
    float* w_out = x_out + (size_t)NB * S_LEN * DM;     // [8,16,1024,1024]

    // workspace layout (bf16 elements)
    bf16* wsb  = (bf16*)d_ws;
    bf16* Wqb  = wsb;                       // 1M elems
    bf16* Wkb  = wsb + 1048576;
    bf16* Wvb  = wsb + 2097152;
    bf16* Wob  = wsb + 3145728;
    bf16* Qp   = wsb + 4194304;             // [N,H,S,D]  8.39M elems
    bf16* Kp   = wsb + 12582912;            // [N,H,S,D]
    bf16* VpT  = wsb + 20971520;            // [N,H,D,S]
    bf16* ctx  = wsb + 29360128;            // [N,S,DM]

    // 1. cast weights to bf16
    cast_weights<<<4096, 256, 0, stream>>>(Wq, Wk, Wv, Wo, Wqb);

    // 2-4. projections (M=8192, N=1024, K=1024)
    gemm_nt<128, 128, 1, EPI_HEADS><<<dim3(64, 8, 1), 256, 0, stream>>>(
        q, Wqb, bq, Qp, 0, 0);
    gemm_nt<128, 128, 1, EPI_HEADS><<<dim3(64, 8, 1), 256, 0, stream>>>(
        k, Wkb, bk, Kp, 0, 0);
    gemm_nt<128, 128, 1, EPI_VT><<<dim3(64, 8, 1), 256, 0, stream>>>(
        v, Wvb, bv, VpT, 0, 0);

    // 5. scores + softmax -> w
    attn_softmax<<<dim3(64, NH, NB), 256, 0, stream>>>(Qp, Kp, pad, w_out);

    // 6. PV: batched (per b,h) GEMM: ctx = w @ Vp  (A = w fp32, B = VpT bf16)
    gemm_nt<128, 64, 1, EPI_CTX><<<dim3(8, 1, NB * NH), 256, 0, stream>>>(
        w_out, VpT, nullptr, ctx, (long)S_LEN * S_LEN, (long)HD * S_LEN);

    // 7. output projection: x = ctx @ Wo^T + bo
    gemm_nt<128, 128, 0, EPI_OUT><<<dim3(64, 8, 1), 256, 0, stream>>>(
        ctx, Wob, bo, x_out, 0, 0);
}

// Round 2
// 1073.536 us; speedup vs baseline: 1.0200x; 1.0200x over previous
//
#include <hip/hip_runtime.h>

typedef __bf16 bf16;
typedef bf16 bf16x8 __attribute__((ext_vector_type(8)));
typedef bf16 bf16x4 __attribute__((ext_vector_type(4)));
typedef float f32x4 __attribute__((ext_vector_type(4)));

#define S_LEN 1024
#define DM    1024
#define NH    16
#define HD    64
#define NB    8
#define NEGV  (-1e9f)

// epilogue modes
#define EPI_HEADS 0  // write bf16 [N,H,S,D]  (Q,K projections)
#define EPI_VT    1  // write bf16 [N,H,D,S]  (V projection, transposed)
#define EPI_OUT   2  // write fp32 [M,N] + bias (final projection)

// ---------------------------------------------------------------------------
// async global->LDS, 16B per lane, wave-uniform LDS base (+lane*16 in HW)
// ---------------------------------------------------------------------------
__device__ __forceinline__ void async16(const bf16* g, const bf16* l) {
    __builtin_amdgcn_global_load_lds(
        (const __attribute__((address_space(1))) void*)g,
        (__attribute__((address_space(3))) void*)l, 16, 0, 0);
}

// ---------------------------------------------------------------------------
// Cast q,k,v (8.39M elems each) + 4 weights (1.05M each) fp32 -> bf16.
// Segments laid out back-to-back in ws: [Qc Kc Vc Wqb Wkb Wvb Wob].
// ---------------------------------------------------------------------------
__global__ __launch_bounds__(256) void cast_all(
    const float* __restrict__ q, const float* __restrict__ k,
    const float* __restrict__ v, const float* __restrict__ wq,
    const float* __restrict__ wk, const float* __restrict__ wv,
    const float* __restrict__ wo, bf16* __restrict__ out)
{
    size_t idx = ((size_t)blockIdx.x * 256 + threadIdx.x) * 4;
    const float* src;
    size_t soff;
    if (idx < 25165824) {                 // 3 x 8388608
        int seg = (int)(idx >> 23);
        soff = idx & 8388607;
        src = seg == 0 ? q : (seg == 1 ? k : v);
    } else {
        size_t r = idx - 25165824;
        int seg = (int)(r >> 20);
        soff = r & 1048575;
        src = seg == 0 ? wq : (seg == 1 ? wk : (seg == 2 ? wv : wo));
    }
    float4 val = *(const float4*)&src[soff];
    bf16x4 o = {(bf16)val.x, (bf16)val.y, (bf16)val.z, (bf16)val.w};
    *(bf16x4*)&out[idx] = o;
}

// ---------------------------------------------------------------------------
// NT GEMM (m97-style): C[M,1024] = A[M,1024] @ B[1024,1024]^T (+bias).
// A,B bf16. 128x128 tile, BK=32, global_load_lds width-16 staging.
// ---------------------------------------------------------------------------
template<int EPI>
__global__ __launch_bounds__(256) void gemm_nt(
    const bf16* __restrict__ Ap, const bf16* __restrict__ Bp,
    const float* __restrict__ bias, void* __restrict__ Cp)
{
    __shared__ bf16 As[128][32];
    __shared__ bf16 Bs[128][32];

    const int tid    = threadIdx.x;
    const int l      = tid & 63;
    const int wid    = tid >> 6;
    const int wr     = wid >> 1, wc = wid & 1;
    const int lane15 = l & 15, quad = l >> 4;
    const int row0   = blockIdx.x * 128;
    const int col0   = blockIdx.y * 128;

    f32x4 acc[4][4];
    #pragma unroll
    for (int i = 0; i < 4; ++i)
        #pragma unroll
        for (int j = 0; j < 4; ++j)
            acc[i][j] = (f32x4){0.f, 0.f, 0.f, 0.f};

    for (int k0 = 0; k0 < 1024; k0 += 32) {
        // stage A and B tiles (each 128x32 bf16 = 8 KB = 8 wave-calls)
        #pragma unroll
        for (int j = 0; j < 2; ++j) {
            int cbase = j * 256 + wid * 64;     // wave-uniform chunk base
            int c = cbase + l;
            int r = c >> 2, kc = (c & 3) << 3;
            async16(&Ap[(size_t)(row0 + r) * 1024 + k0 + kc], &As[0][0] + cbase * 8);
            async16(&Bp[(size_t)(col0 + r) * 1024 + k0 + kc], &Bs[0][0] + cbase * 8);
        }
        __syncthreads();

        bf16x8 afr[4], bfr[4];
        #pragma unroll
        for (int tm = 0; tm < 4; ++tm)
            afr[tm] = *(const bf16x8*)&As[wr * 64 + tm * 16 + lane15][quad * 8];
        #pragma unroll
        for (int tn = 0; tn < 4; ++tn)
            bfr[tn] = *(const bf16x8*)&Bs[wc * 64 + tn * 16 + lane15][quad * 8];
        #pragma unroll
        for (int tm = 0; tm < 4; ++tm)
            #pragma unroll
            for (int tn = 0; tn < 4; ++tn)
                acc[tm][tn] = __builtin_amdgcn_mfma_f32_16x16x32_bf16(
                    afr[tm], bfr[tn], acc[tm][tn], 0, 0, 0);
        __syncthreads();
    }

    // ---- epilogue ----
    #pragma unroll
    for (int tm = 0; tm < 4; ++tm) {
        #pragma unroll
        for (int tn = 0; tn < 4; ++tn) {
            #pragma unroll
            for (int i = 0; i < 4; ++i) {
                int gr = row0 + wr * 64 + tm * 16 + quad * 4 + i;
                int gc = col0 + wc * 64 + tn * 16 + lane15;
                float vout = acc[tm][tn][i] + bias[gc];
                if constexpr (EPI == EPI_HEADS) {
                    int n = gr >> 10, s = gr & 1023, h = gc >> 6, d = gc & 63;
                    ((bf16*)Cp)[(((size_t)(n * NH + h) * S_LEN + s) << 6) + d] = (bf16)vout;
                } else if constexpr (EPI == EPI_VT) {
                    int n = gr >> 10, s = gr & 1023, h = gc >> 6, d = gc & 63;
                    ((bf16*)Cp)[(((size_t)(n * NH + h) * HD + d) << 10) + s] = (bf16)vout;
                } else { // EPI_OUT
                    ((float*)Cp)[(size_t)gr * DM + gc] = vout;
                }
            }
        }
    }
}

// ---------------------------------------------------------------------------
// Fused scores + softmax + PV: per block = one (n, h, 16-q-row) tile.
// 4 waves; wave w owns key columns [256w, 256w+256) for QK/softmax, then
// d-columns [16w, 16w+16) for PV after the P round-trip through LDS.
// Writes normalized w (fp32) AND ctx (bf16, [N,S,DM]).
// ---------------------------------------------------------------------------
__global__ __launch_bounds__(256) void attn_fused(
    const bf16* __restrict__ Qp, const bf16* __restrict__ Kp,
    const bf16* __restrict__ VpT, const int* __restrict__ pad,
    float* __restrict__ Wout, bf16* __restrict__ ctx)
{
    const int qblk = blockIdx.x;
    const int h = blockIdx.y, n = blockIdx.z;
    const int bh = n * NH + h;
    const bf16* Qb = Qp + (size_t)bh * S_LEN * HD;
    const bf16* Kb = Kp + (size_t)bh * S_LEN * HD;
    const bf16* Vb = VpT + (size_t)bh * HD * S_LEN;
    float* Wb = Wout + (size_t)bh * S_LEN * S_LEN;

    const int tid = threadIdx.x;
    const int l = tid & 63, wid = tid >> 6;
    const int lane15 = l & 15, quad = l >> 4;
    const int q0 = qblk * 16;

    __shared__ int   padLds[S_LEN];
    __shared__ float redM[4][16];
    __shared__ float redS[4][16];
    __shared__ bf16  P[16][1032];       // +8 pad: row stride 2064 B -> conflict-free-ish
    for (int i = tid; i < S_LEN; i += 256) padLds[i] = pad[n * S_LEN + i];

    bf16x8 a0 = *(const bf16x8*)&Qb[(size_t)(q0 + lane15) * HD + quad * 8];
    bf16x8 a1 = *(const bf16x8*)&Qb[(size_t)(q0 + lane15) * HD + 32 + quad * 8];
    __syncthreads();

    f32x4 sc[16];
    const int colbase = wid * 256;
    #pragma unroll
    for (int t = 0; t < 16; ++t) {
        int c0 = colbase + t * 16;
        bf16x8 b0 = *(const bf16x8*)&Kb[(size_t)(c0 + lane15) * HD + quad * 8];
        bf16x8 b1 = *(const bf16x8*)&Kb[(size_t)(c0 + lane15) * HD + 32 + quad * 8];
        f32x4 a = (f32x4){0.f, 0.f, 0.f, 0.f};
        a = __builtin_amdgcn_mfma_f32_16x16x32_bf16(a0, b0, a, 0, 0, 0);
        a = __builtin_amdgcn_mfma_f32_16x16x32_bf16(a1, b1, a, 0, 0, 0);
        sc[t] = a;
    }

    // scale + causal/padding mask (exactly -1e9, like the reference)
    #pragma unroll
    for (int t = 0; t < 16; ++t) {
        int col = colbase + t * 16 + lane15;
        int pd = padLds[col];
        #pragma unroll
        for (int i = 0; i < 4; ++i) {
            int row = q0 + quad * 4 + i;
            float v = sc[t][i] * 0.03125f;   // 1/sqrt(1024)
            sc[t][i] = (col > row || pd != 0) ? NEGV : v;
        }
    }

    // row max
    float m[4];
    #pragma unroll
    for (int i = 0; i < 4; ++i) {
        float mm = sc[0][i];
        #pragma unroll
        for (int t = 1; t < 16; ++t) mm = fmaxf(mm, sc[t][i]);
        #pragma unroll
        for (int dlt = 1; dlt < 16; dlt <<= 1) mm = fmaxf(mm, __shfl_xor(mm, dlt));
        m[i] = mm;
    }
    if (lane15 == 0) {
        #pragma unroll
        for (int i = 0; i < 4; ++i) redM[wid][quad * 4 + i] = m[i];
    }
    __syncthreads();
    #pragma unroll
    for (int i = 0; i < 4; ++i) {
        int row = quad * 4 + i;
        m[i] = fmaxf(fmaxf(redM[0][row], redM[1][row]),
                     fmaxf(redM[2][row], redM[3][row]));
    }

    // exp + row sum
    float sm[4] = {0.f, 0.f, 0.f, 0.f};
    #pragma unroll
    for (int t = 0; t < 16; ++t)
        #pragma unroll
        for (int i = 0; i < 4; ++i) {
            float p = __expf(sc[t][i] - m[i]);
            sc[t][i] = p;
            sm[i] += p;
        }
    #pragma unroll
    for (int i = 0; i < 4; ++i) {
        #pragma unroll
        for (int dlt = 1; dlt < 16; dlt <<= 1) sm[i] += __shfl_xor(sm[i], dlt);
    }
    if (lane15 == 0) {
        #pragma unroll
        for (int i = 0; i < 4; ++i) redS[wid][quad * 4 + i] = sm[i];
    }
    __syncthreads();
    float inv[4];
    #pragma unroll
    for (int i = 0; i < 4; ++i) {
        int row = quad * 4 + i;
        inv[i] = 1.f / (redS[0][row] + redS[1][row] + redS[2][row] + redS[3][row]);
    }

    // write normalized w + stash P (bf16) in LDS for the PV stage
    #pragma unroll
    for (int t = 0; t < 16; ++t)
        #pragma unroll
        for (int i = 0; i < 4; ++i) {
            float p = sc[t][i] * inv[i];
            int row = quad * 4 + i;
            int col = colbase + t * 16 + lane15;
            Wb[(size_t)(q0 + row) * S_LEN + col] = p;
            P[row][col] = (bf16)p;
        }
    __syncthreads();

    // PV: wave wid computes ctx tile [16 q-rows] x [d = 16*wid .. +16)
    const int dbase = wid * 16;
    f32x4 o = (f32x4){0.f, 0.f, 0.f, 0.f};
    #pragma unroll 4
    for (int k0 = 0; k0 < S_LEN; k0 += 32) {
        bf16x8 a = *(const bf16x8*)&P[lane15][k0 + quad * 8];
        bf16x8 b = *(const bf16x8*)&Vb[(size_t)(dbase + lane15) * S_LEN + k0 + quad * 8];
        o = __builtin_amdgcn_mfma_f32_16x16x32_bf16(a, b, o, 0, 0, 0);
    }
    #pragma unroll
    for (int i = 0; i < 4; ++i) {
        int row = q0 + quad * 4 + i;
        ctx[((size_t)(n * S_LEN + row) << 10) + h * HD + dbase + lane15] = (bf16)o[i];
    }
}

// ---------------------------------------------------------------------------
extern "C" void kernel_launch(void* const* d_in, const int* in_sizes, int n_in,
                              void* d_out, int out_size, void* d_ws, size_t ws_size,
                              hipStream_t stream)
{
    const float* q   = (const float*)d_in[0];
    const float* k   = (const float*)d_in[1];
    const float* v   = (const float*)d_in[2];
    // d_in[3] = causal_mask -- computed arithmetically
    const int*   pad = (const int*)  d_in[4];
    const float* Wq  = (const float*)d_in[5];
    const float* bq  = (const float*)d_in[6];
    const float* Wk  = (const float*)d_in[7];
    const float* bk  = (const float*)d_in[8];
    const float* Wv  = (const float*)d_in[9];
    const float* bv  = (const float*)d_in[10];
    const float* Wo  = (const float*)d_in[11];
    const float* bo  = (const float*)d_in[12];

    float* x_out = (float*)d_out;                       // [8,1024,1024]
    float* w_out = x_out + (size_t)NB * S_LEN * DM;     // [8,16,1024,1024]

    // workspace layout (bf16 elements)
    bf16* wsb = (bf16*)d_ws;
    bf16* Qc  = wsb;                    // cast inputs: 3 x 8388608
    bf16* Wqb = wsb + 25165824;         // cast weights: 4 x 1048576
    bf16* Wkb = wsb + 26214400;
    bf16* Wvb = wsb + 27262976;
    bf16* Wob = wsb + 28311552;
    bf16* Qp  = wsb + 29360128;         // [N,H,S,D]
    bf16* Kp  = wsb + 37748736;         // [N,H,S,D]
    bf16* VpT = wsb + 46137344;         // [N,H,D,S]
    bf16* ctx = wsb + 54525952;         // [N,S,DM]
    bf16* Kc  = Qc + 8388608;
    bf16* Vc  = Qc + 16777216;

    // 1. cast everything to bf16 (29360128 elems / 4 per thread)
    cast_all<<<28672, 256, 0, stream>>>(q, k, v, Wq, Wk, Wv, Wo, wsb);

    // 2-4. projections (M=8192, N=1024, K=1024), m97-style
    gemm_nt<EPI_HEADS><<<dim3(64, 8), 256, 0, stream>>>(Qc, Wqb, bq, Qp);
    gemm_nt<EPI_HEADS><<<dim3(64, 8), 256, 0, stream>>>(Kc, Wkb, bk, Kp);
    gemm_nt<EPI_VT>   <<<dim3(64, 8), 256, 0, stream>>>(Vc, Wvb, bv, VpT);

    // 5. fused scores + softmax + PV -> w_out, ctx
    attn_fused<<<dim3(64, NH, NB), 256, 0, stream>>>(Qp, Kp, VpT, pad, w_out, ctx);

    // 6. output projection: x = ctx @ Wo^T + bo
    gemm_nt<EPI_OUT><<<dim3(64, 8), 256, 0, stream>>>(ctx, Wob, bo, x_out);
}

// Round 3
// 958.953 us; speedup vs baseline: 1.1419x; 1.1195x over previous
//
#include <hip/hip_runtime.h>

typedef __bf16 bf16;
typedef bf16 bf16x8 __attribute__((ext_vector_type(8)));
typedef bf16 bf16x4 __attribute__((ext_vector_type(4)));
typedef float f32x4 __attribute__((ext_vector_type(4)));

#define S_LEN 1024
#define DM    1024
#define NH    16
#define HD    64
#define NB    8
#define NEGV  (-1e9f)

// epilogue modes
#define EPI_HEADS 0  // write bf16 [N,H,S,D]  (Q,K projections)
#define EPI_VT    1  // write bf16 [N,H,D,S]  (V projection, transposed)
#define EPI_OUT   2  // write fp32 [M,N] + bias (final projection)

// ---------------------------------------------------------------------------
// async global->LDS, 16B per lane, wave-uniform LDS base (+lane*16 in HW)
// ---------------------------------------------------------------------------
__device__ __forceinline__ void async16(const bf16* g, const bf16* l) {
    __builtin_amdgcn_global_load_lds(
        (const __attribute__((address_space(1))) void*)g,
        (__attribute__((address_space(3))) void*)l, 16, 0, 0);
}

// ---------------------------------------------------------------------------
// Cast q,k,v (8.39M elems each) + 4 weights (1.05M each) fp32 -> bf16.
// Segments laid out back-to-back in ws: [Qc Kc Vc Wqb Wkb Wvb Wob].
// ---------------------------------------------------------------------------
__global__ __launch_bounds__(256) void cast_all(
    const float* __restrict__ q, const float* __restrict__ k,
    const float* __restrict__ v, const float* __restrict__ wq,
    const float* __restrict__ wk, const float* __restrict__ wv,
    const float* __restrict__ wo, bf16* __restrict__ out)
{
    size_t idx = ((size_t)blockIdx.x * 256 + threadIdx.x) * 4;
    const float* src;
    size_t soff;
    if (idx < 25165824) {                 // 3 x 8388608
        int seg = (int)(idx >> 23);
        soff = idx & 8388607;
        src = seg == 0 ? q : (seg == 1 ? k : v);
    } else {
        size_t r = idx - 25165824;
        int seg = (int)(r >> 20);
        soff = r & 1048575;
        src = seg == 0 ? wq : (seg == 1 ? wk : (seg == 2 ? wv : wo));
    }
    float4 val = *(const float4*)&src[soff];
    bf16x4 o = {(bf16)val.x, (bf16)val.y, (bf16)val.z, (bf16)val.w};
    *(bf16x4*)&out[idx] = o;
}

// ---------------------------------------------------------------------------
// NT GEMM (m97-style): C[M,1024] = A[M,1024] @ B[1024,1024]^T (+bias).
// A,B bf16. 128x128 tile, BK=32, global_load_lds width-16 staging.
// ---------------------------------------------------------------------------
template<int EPI>
__global__ __launch_bounds__(256) void gemm_nt(
    const bf16* __restrict__ Ap, const bf16* __restrict__ Bp,
    const float* __restrict__ bias, void* __restrict__ Cp)
{
    __shared__ bf16 As[128][32];
    __shared__ bf16 Bs[128][32];

    const int tid    = threadIdx.x;
    const int l      = tid & 63;
    const int wid    = tid >> 6;
    const int wr     = wid >> 1, wc = wid & 1;
    const int lane15 = l & 15, quad = l >> 4;
    const int row0   = blockIdx.x * 128;
    const int col0   = blockIdx.y * 128;

    f32x4 acc[4][4];
    #pragma unroll
    for (int i = 0; i < 4; ++i)
        #pragma unroll
        for (int j = 0; j < 4; ++j)
            acc[i][j] = (f32x4){0.f, 0.f, 0.f, 0.f};

    for (int k0 = 0; k0 < 1024; k0 += 32) {
        #pragma unroll
        for (int j = 0; j < 2; ++j) {
            int cbase = j * 256 + wid * 64;     // wave-uniform chunk base
            int c = cbase + l;
            int r = c >> 2, kc = (c & 3) << 3;
            async16(&Ap[(size_t)(row0 + r) * 1024 + k0 + kc], &As[0][0] + cbase * 8);
            async16(&Bp[(size_t)(col0 + r) * 1024 + k0 + kc], &Bs[0][0] + cbase * 8);
        }
        __syncthreads();

        bf16x8 afr[4], bfr[4];
        #pragma unroll
        for (int tm = 0; tm < 4; ++tm)
            afr[tm] = *(const bf16x8*)&As[wr * 64 + tm * 16 + lane15][quad * 8];
        #pragma unroll
        for (int tn = 0; tn < 4; ++tn)
            bfr[tn] = *(const bf16x8*)&Bs[wc * 64 + tn * 16 + lane15][quad * 8];
        #pragma unroll
        for (int tm = 0; tm < 4; ++tm)
            #pragma unroll
            for (int tn = 0; tn < 4; ++tn)
                acc[tm][tn] = __builtin_amdgcn_mfma_f32_16x16x32_bf16(
                    afr[tm], bfr[tn], acc[tm][tn], 0, 0, 0);
        __syncthreads();
    }

    #pragma unroll
    for (int tm = 0; tm < 4; ++tm) {
        #pragma unroll
        for (int tn = 0; tn < 4; ++tn) {
            #pragma unroll
            for (int i = 0; i < 4; ++i) {
                int gr = row0 + wr * 64 + tm * 16 + quad * 4 + i;
                int gc = col0 + wc * 64 + tn * 16 + lane15;
                float vout = acc[tm][tn][i] + bias[gc];
                if constexpr (EPI == EPI_HEADS) {
                    int n = gr >> 10, s = gr & 1023, h = gc >> 6, d = gc & 63;
                    ((bf16*)Cp)[(((size_t)(n * NH + h) * S_LEN + s) << 6) + d] = (bf16)vout;
                } else if constexpr (EPI == EPI_VT) {
                    int n = gr >> 10, s = gr & 1023, h = gc >> 6, d = gc & 63;
                    ((bf16*)Cp)[(((size_t)(n * NH + h) * HD + d) << 10) + s] = (bf16)vout;
                } else { // EPI_OUT
                    ((float*)Cp)[(size_t)gr * DM + gc] = vout;
                }
            }
        }
    }
}

// ---------------------------------------------------------------------------
// Fused scores + softmax + PV, S^T formulation.
// Block = one (n, h, 16-q-row) tile, 4 waves; wave w owns keys [256w,256w+256).
// MFMA computes S^T = K*Q^T so each lane holds q=lane15, keys=quad*4+i+16t
// -> float4 w-stores, bf16x4 P-stores, int4 pad loads, in-lane row reductions.
// Causal skipping: tiles/chunks fully above the diagonal skip MFMA + loads.
// Degenerate (all-masked) rows handled exactly via the analytic skip term.
// ---------------------------------------------------------------------------
__global__ __launch_bounds__(256, 4) void attn_fused(
    const bf16* __restrict__ Qp, const bf16* __restrict__ Kp,
    const bf16* __restrict__ VpT, const int* __restrict__ pad,
    float* __restrict__ Wout, bf16* __restrict__ ctx)
{
    const int qblk = blockIdx.x;
    const int h = blockIdx.y, n = blockIdx.z;
    const int bh = n * NH + h;
    const bf16* Qb = Qp + (size_t)bh * S_LEN * HD;
    const bf16* Kb = Kp + (size_t)bh * S_LEN * HD;
    const bf16* Vb = VpT + (size_t)bh * HD * S_LEN;
    float* Wb = Wout + (size_t)bh * S_LEN * S_LEN;

    const int tid = threadIdx.x;
    const int l = tid & 63, wid = tid >> 6;
    const int lane15 = l & 15, quad = l >> 4;
    const int q0 = qblk * 16;
    const int q = q0 + lane15;          // this lane's q-row
    const int qmax = q0 + 15;

    __shared__ bf16  P[16][1032];       // normalized probs, [q][key], A-frag layout
    __shared__ float redM[4][16];
    __shared__ float redS[4][16];

    // Q fragment (B-operand: n=lane15 -> q-row, k=quad*8 -> d)
    bf16x8 qf0 = *(const bf16x8*)&Qb[(size_t)q * HD + quad * 8];
    bf16x8 qf1 = *(const bf16x8*)&Qb[(size_t)q * HD + 32 + quad * 8];

    const int keyw = wid * 256;
    f32x4 sc[16];
    float mm = NEGV;

    #pragma unroll
    for (int t = 0; t < 16; ++t) {
        int kb = keyw + t * 16;
        if (kb <= qmax) {               // wave-uniform causal tile filter
            bf16x8 kf0 = *(const bf16x8*)&Kb[(size_t)(kb + lane15) * HD + quad * 8];
            bf16x8 kf1 = *(const bf16x8*)&Kb[(size_t)(kb + lane15) * HD + 32 + quad * 8];
            f32x4 a = (f32x4){0.f, 0.f, 0.f, 0.f};
            a = __builtin_amdgcn_mfma_f32_16x16x32_bf16(kf0, qf0, a, 0, 0, 0);
            a = __builtin_amdgcn_mfma_f32_16x16x32_bf16(kf1, qf1, a, 0, 0, 0);
            int4 pd = *(const int4*)&pad[n * S_LEN + kb + quad * 4];
            const int* pdi = (const int*)&pd;
            int key0 = kb + quad * 4;
            #pragma unroll
            for (int i = 0; i < 4; ++i) {
                float v = a[i] * 0.03125f;                  // 1/sqrt(1024)
                a[i] = (key0 + i > q || pdi[i] != 0) ? NEGV : v;
            }
            sc[t] = a;
            mm = fmaxf(mm, fmaxf(fmaxf(a[0], a[1]), fmaxf(a[2], a[3])));
        }
    }

    // row max: cross-quad then cross-wave
    mm = fmaxf(mm, __shfl_xor(mm, 16));
    mm = fmaxf(mm, __shfl_xor(mm, 32));
    if (l < 16) redM[wid][l] = mm;
    __syncthreads();
    float m = fmaxf(fmaxf(redM[0][lane15], redM[1][lane15]),
                    fmaxf(redM[2][lane15], redM[3][lane15]));

    // skip term: value of exp(-1e9 - m). 0 for normal rows, 1 for all-masked.
    float vskip = __expf(NEGV - m);

    // exp + row partial sum (skipped tiles contribute analytically)
    float sm = 0.f;
    #pragma unroll
    for (int t = 0; t < 16; ++t) {
        int kb = keyw + t * 16;
        if (kb <= qmax) {
            #pragma unroll
            for (int i = 0; i < 4; ++i) {
                float p = __expf(sc[t][i] - m);
                sc[t][i] = p;
                sm += p;
            }
        } else {
            sm += 4.f * vskip;          // 4 keys/lane; x4 quads via shuffles
        }
    }
    sm += __shfl_xor(sm, 16);
    sm += __shfl_xor(sm, 32);
    if (l < 16) redS[wid][l] = sm;
    __syncthreads();
    float inv = 1.f / (redS[0][lane15] + redS[1][lane15] +
                       redS[2][lane15] + redS[3][lane15]);
    float wskip = vskip * inv;
    bool anyDeg = __ballot(m == NEGV) != 0;   // wave-uniform, same all waves

    // write normalized w (float4) + P (bf16x4)
    #pragma unroll
    for (int t = 0; t < 16; ++t) {
        int kb = keyw + t * 16;
        int off = kb + quad * 4;
        if (kb <= qmax) {
            float4 wv = {sc[t][0] * inv, sc[t][1] * inv,
                         sc[t][2] * inv, sc[t][3] * inv};
            *(float4*)&Wb[(size_t)q * S_LEN + off] = wv;
            bf16x4 pb = {(bf16)wv.x, (bf16)wv.y, (bf16)wv.z, (bf16)wv.w};
            *(bf16x4*)&P[lane15][off] = pb;
        } else {
            float4 wv = {wskip, wskip, wskip, wskip};
            *(float4*)&Wb[(size_t)q * S_LEN + off] = wv;
            bf16 pv = (bf16)wskip;
            bf16x4 pb = {pv, pv, pv, pv};
            *(bf16x4*)&P[lane15][off] = pb;
        }
    }
    __syncthreads();

    // PV: wave wid computes ctx tile [16 q-rows] x [d = 16*wid .. +16)
    const int dbase = wid * 16;
    const int cEnd = anyDeg ? 32 : ((qmax >> 5) + 1);   // causal chunk skip
    f32x4 o = (f32x4){0.f, 0.f, 0.f, 0.f};
    #pragma unroll 4
    for (int c = 0; c < cEnd; ++c) {
        bf16x8 a = *(const bf16x8*)&P[lane15][c * 32 + quad * 8];
        bf16x8 b = *(const bf16x8*)&Vb[(size_t)(dbase + lane15) * S_LEN + c * 32 + quad * 8];
        o = __builtin_amdgcn_mfma_f32_16x16x32_bf16(a, b, o, 0, 0, 0);
    }
    #pragma unroll
    for (int i = 0; i < 4; ++i) {
        int row = q0 + quad * 4 + i;
        ctx[((size_t)(n * S_LEN + row) << 10) + h * HD + dbase + lane15] = (bf16)o[i];
    }
}

// ---------------------------------------------------------------------------
extern "C" void kernel_launch(void* const* d_in, const int* in_sizes, int n_in,
                              void* d_out, int out_size, void* d_ws, size_t ws_size,
                              hipStream_t stream)
{
    const float* q   = (const float*)d_in[0];
    const float* k   = (const float*)d_in[1];
    const float* v   = (const float*)d_in[2];
    // d_in[3] = causal_mask -- computed arithmetically
    const int*   pad = (const int*)  d_in[4];
    const float* Wq  = (const float*)d_in[5];
    const float* bq  = (const float*)d_in[6];
    const float* Wk  = (const float*)d_in[7];
    const float* bk  = (const float*)d_in[8];
    const float* Wv  = (const float*)d_in[9];
    const float* bv  = (const float*)d_in[10];
    const float* Wo  = (const float*)d_in[11];
    const float* bo  = (const float*)d_in[12];

    float* x_out = (float*)d_out;                       // [8,1024,1024]
    float* w_out = x_out + (size_t)NB * S_LEN * DM;     // [8,16,1024,1024]

    // workspace layout (bf16 elements)
    bf16* wsb = (bf16*)d_ws;
    bf16* Qc  = wsb;                    // cast inputs: 3 x 8388608
    bf16* Wqb = wsb + 25165824;         // cast weights: 4 x 1048576
    bf16* Wkb = wsb + 26214400;
    bf16* Wvb = wsb + 27262976;
    bf16* Wob = wsb + 28311552;
    bf16* Qp  = wsb + 29360128;         // [N,H,S,D]
    bf16* Kp  = wsb + 37748736;         // [N,H,S,D]
    bf16* VpT = wsb + 46137344;         // [N,H,D,S]
    bf16* ctx = wsb + 54525952;         // [N,S,DM]
    bf16* Kc  = Qc + 8388608;
    bf16* Vc  = Qc + 16777216;

    // 1. cast everything to bf16 (29360128 elems / 4 per thread)
    cast_all<<<28672, 256, 0, stream>>>(q, k, v, Wq, Wk, Wv, Wo, wsb);

    // 2-4. projections (M=8192, N=1024, K=1024), m97-style
    gemm_nt<EPI_HEADS><<<dim3(64, 8), 256, 0, stream>>>(Qc, Wqb, bq, Qp);
    gemm_nt<EPI_HEADS><<<dim3(64, 8), 256, 0, stream>>>(Kc, Wkb, bk, Kp);
    gemm_nt<EPI_VT>   <<<dim3(64, 8), 256, 0, stream>>>(Vc, Wvb, bv, VpT);

    // 5. fused scores + softmax + PV -> w_out, ctx
    attn_fused<<<dim3(64, NH, NB), 256, 0, stream>>>(Qp, Kp, VpT, pad, w_out, ctx);

    // 6. output projection: x = ctx @ Wo^T + bo
    gemm_nt<EPI_OUT><<<dim3(64, 8), 256, 0, stream>>>(ctx, Wob, bo, x_out);
}